// Round 1
// baseline (212.857 us; speedup 1.0000x reference)
//
#include <hip/hip_runtime.h>
#include <hip/hip_bf16.h>

#define HH 8
#define DKK 32
#define DM 256
#define NN 512
#define DE 40
#define DHID 32

__device__ __forceinline__ unsigned int pack_bf16x2(float a, float b) {
    union { __hip_bfloat16 h; unsigned short u; } ua, ub;
    ua.h = __float2bfloat16(a);
    ub.h = __float2bfloat16(b);
    return (unsigned int)ua.u | ((unsigned int)ub.u << 16);
}
__device__ __forceinline__ float bf16_bits_to_f(unsigned int u16) {
    return __uint_as_float(u16 << 16);
}

// ---------------- Q/K/V projection: 4 rows per block ----------------
__global__ __launch_bounds__(256) void proj_kernel(
    const float* __restrict__ query, const float* __restrict__ key_,
    const float* __restrict__ value,
    const float* __restrict__ Wq, const float* __restrict__ bq,
    const float* __restrict__ Wk, const float* __restrict__ bk,
    const float* __restrict__ Wv, const float* __restrict__ bv,
    float* __restrict__ Q, float* __restrict__ K, float* __restrict__ V)
{
    const int r0 = blockIdx.x * 4;
    const int c = threadIdx.x;
    float aq[4], ak[4], av[4];
    const float bqc = bq[c], bkc = bk[c], bvc = bv[c];
#pragma unroll
    for (int r = 0; r < 4; ++r) { aq[r] = bqc; ak[r] = bkc; av[r] = bvc; }
    for (int k = 0; k < DM; ++k) {
        const float wq = Wq[k*DM + c];
        const float wk = Wk[k*DM + c];
        const float wv = Wv[k*DM + c];
#pragma unroll
        for (int r = 0; r < 4; ++r) {
            // query[(r0+r)*DM + k] is wave-uniform -> scalar loads
            aq[r] = fmaf(query[(size_t)(r0+r)*DM + k], wq, aq[r]);
            ak[r] = fmaf(key_ [(size_t)(r0+r)*DM + k], wk, ak[r]);
            av[r] = fmaf(value[(size_t)(r0+r)*DM + k], wv, av[r]);
        }
    }
#pragma unroll
    for (int r = 0; r < 4; ++r) {
        Q[(size_t)(r0+r)*DM + c] = aq[r];
        K[(size_t)(r0+r)*DM + c] = ak[r];
        V[(size_t)(r0+r)*DM + c] = av[r];
    }
}

// ---------------- fused relative attention: one block per (b,i) row ----------------
__global__ __launch_bounds__(256) void attn_kernel(
    const float* __restrict__ edges, const int* __restrict__ mask,
    const float* __restrict__ rkW1, const float* __restrict__ rkb1,
    const float* __restrict__ rkW2, const float* __restrict__ rkb2,
    const float* __restrict__ rvW1, const float* __restrict__ rvb1,
    const float* __restrict__ rvW2, const float* __restrict__ rvb2,
    const float* __restrict__ vvec,
    const float* __restrict__ Wo, const float* __restrict__ bo,
    const float* __restrict__ Q, const float* __restrict__ K, const float* __restrict__ V,
    float* __restrict__ out)
{
    const int bi = blockIdx.x;          // b*512 + i
    const int b  = bi >> 9;
    const int i  = bi & 511;
    const int tid = threadIdx.x;
    const float inv = 0.17677669529663687f; // 1/sqrt(32)

    __shared__ __align__(16) float sc[HH*520];           // scores -> p  (row stride 520: 2-way max)
    __shared__ unsigned int h1vl[NN*17];                 // h1v as bf16x2, 16 dwords + 1 pad per j
    __shared__ __align__(16) float wf[DM];
    __shared__ float gK[HH*33];
    __shared__ float c0K[HH];
    __shared__ float A_l[HH*33];
    __shared__ float o_l[DM];

    // ---- phase 0a: w = inv*(q+k) + v  (per row-i channel) ----
    {
        const float qv = Q[(size_t)bi*DM + tid];
        const float kv = K[(size_t)bi*DM + tid];
        wf[tid] = inv*(qv + kv) + vvec[tid];
    }
    __syncthreads();

    // ---- phase 0b: gK[h,t] = sum_d rkW2[t, h*32+d] * w[h,d];  c0K[h] = b2k . w ----
    {
        const int h = tid >> 5, t = tid & 31;
        float acc = 0.f;
#pragma unroll
        for (int d4 = 0; d4 < DKK/4; ++d4) {
            const float4 w4 = *(const float4*)(rkW2 + (size_t)t*DM + h*DKK + d4*4);
            const float4 f4 = *(const float4*)(&wf[h*DKK + d4*4]);
            acc = fmaf(w4.x, f4.x, acc); acc = fmaf(w4.y, f4.y, acc);
            acc = fmaf(w4.z, f4.z, acc); acc = fmaf(w4.w, f4.w, acc);
        }
        gK[h*33 + t] = acc;
        if (tid < HH) {
            float a2 = 0.f;
#pragma unroll
            for (int d = 0; d < DKK; ++d)
                a2 = fmaf(rkb2[tid*DKK + d], wf[tid*DKK + d], a2);
            c0K[tid] = a2;
        }
    }
    __syncthreads();

    // ---- phase 1: per-j edge MLP layer-1, scores, stash h1v ----
    {
        const size_t ebase = (size_t)b*DE*NN*NN + (size_t)i*NN;
        float h1k0[DHID], h1k1[DHID], h1v0[DHID], h1v1[DHID];
#pragma unroll
        for (int t = 0; t < DHID; ++t) {
            const float bk1 = rkb1[t], bv1 = rvb1[t];   // uniform -> scalar
            h1k0[t] = bk1; h1k1[t] = bk1;
            h1v0[t] = bv1; h1v1[t] = bv1;
        }
        for (int c = 0; c < DE; ++c) {
            const float e0 = edges[ebase + (size_t)c*NN*NN + tid];
            const float e1 = edges[ebase + (size_t)c*NN*NN + tid + 256];
#pragma unroll
            for (int t = 0; t < DHID; ++t) {
                const float wk = rkW1[c*DHID + t];      // uniform -> scalar
                const float wv = rvW1[c*DHID + t];
                h1k0[t] = fmaf(e0, wk, h1k0[t]);
                h1k1[t] = fmaf(e1, wk, h1k1[t]);
                h1v0[t] = fmaf(e0, wv, h1v0[t]);
                h1v1[t] = fmaf(e1, wv, h1v1[t]);
            }
        }
#pragma unroll
        for (int t = 0; t < DHID; ++t) {
            h1k0[t] = h1k0[t] > 0.f ? h1k0[t] : 0.1f*h1k0[t];
            h1k1[t] = h1k1[t] > 0.f ? h1k1[t] : 0.1f*h1k1[t];
            h1v0[t] = h1v0[t] > 0.f ? h1v0[t] : 0.1f*h1v0[t];
            h1v1[t] = h1v1[t] > 0.f ? h1v1[t] : 0.1f*h1v1[t];
        }
        // stash h1v (bf16 packed), frees 64 regs
#pragma unroll
        for (int t2 = 0; t2 < 16; ++t2) {
            h1vl[(size_t)tid*17 + t2]       = pack_bf16x2(h1v0[2*t2], h1v0[2*t2+1]);
            h1vl[(size_t)(tid+256)*17 + t2] = pack_bf16x2(h1v1[2*t2], h1v1[2*t2+1]);
        }
        // scores: rel part + q.k
        const int m0 = mask[b*NN + tid];
        const int m1 = mask[b*NN + tid + 256];
        const float* k0p = K + ((size_t)b*NN + tid)*DM;
        const float* k1p = k0p + (size_t)256*DM;
        const float* qrow = Q + (size_t)bi*DM;          // uniform -> scalar loads
#pragma unroll
        for (int h = 0; h < HH; ++h) {
            float r0 = c0K[h], r1 = c0K[h];
#pragma unroll
            for (int t = 0; t < DHID; ++t) {
                const float g = gK[h*33 + t];
                r0 = fmaf(g, h1k0[t], r0);
                r1 = fmaf(g, h1k1[t], r1);
            }
            float a0 = 0.f, a1 = 0.f;
#pragma unroll
            for (int c4 = 0; c4 < DKK/4; ++c4) {
                const int c = h*DKK + c4*4;
                const float4 q4 = *(const float4*)(qrow + c);
                const float4 x0 = *(const float4*)(k0p + c);
                const float4 x1 = *(const float4*)(k1p + c);
                a0 = fmaf(q4.x, x0.x, a0); a0 = fmaf(q4.y, x0.y, a0);
                a0 = fmaf(q4.z, x0.z, a0); a0 = fmaf(q4.w, x0.w, a0);
                a1 = fmaf(q4.x, x1.x, a1); a1 = fmaf(q4.y, x1.y, a1);
                a1 = fmaf(q4.z, x1.z, a1); a1 = fmaf(q4.w, x1.w, a1);
            }
            float v0 = fmaf(inv, a0, r0);
            float v1 = fmaf(inv, a1, r1);
            if (m0 == 0) v0 = -1e12f;
            if (m1 == 0) v1 = -1e12f;
            sc[h*520 + tid]       = v0;
            sc[h*520 + 256 + tid] = v1;
        }
    }
    __syncthreads();

    // ---- phase 2: softmax per head (32 lanes per head) ----
    {
        const int h = tid >> 5, l = tid & 31;
        float m = -3e38f;
#pragma unroll
        for (int k = 0; k < 16; ++k) m = fmaxf(m, sc[h*520 + l + 32*k]);
#pragma unroll
        for (int off = 16; off; off >>= 1) m = fmaxf(m, __shfl_xor(m, off, 32));
        float s = 0.f;
#pragma unroll
        for (int k = 0; k < 16; ++k) {
            const float e = __expf(sc[h*520 + l + 32*k] - m);
            sc[h*520 + l + 32*k] = e;
            s += e;
        }
#pragma unroll
        for (int off = 16; off; off >>= 1) s += __shfl_xor(s, off, 32);
        const float rs = 1.f / s;
#pragma unroll
        for (int k = 0; k < 16; ++k) sc[h*520 + l + 32*k] *= rs;
    }
    __syncthreads();

    // ---- phase 3: o1 = p @ Vproj, A[h,t] = sum_j p*h1v ----
    float acc_o = 0.f;
    {
        const int h = tid >> 5, t = tid & 31;
        float acc_A = 0.f;
        const float* vb = V + (size_t)b*NN*DM;
        for (int j = 0; j < NN; ++j) {
            const float p  = sc[h*520 + j];
            const float vv = vb[(size_t)j*DM + tid];
            acc_o = fmaf(p, vv, acc_o);
            const unsigned int pk = h1vl[(size_t)j*17 + (t >> 1)];
            const float hv = bf16_bits_to_f((t & 1) ? (pk >> 16) : (pk & 0xffffu));
            acc_A = fmaf(p, hv, acc_A);
        }
        A_l[h*33 + t] = acc_A;
    }
    __syncthreads();

    // ---- o2 and merged o ----
    {
        const int h = tid >> 5;
        float o2 = rvb2[tid];
#pragma unroll
        for (int t = 0; t < DHID; ++t)
            o2 = fmaf(A_l[h*33 + t], rvW2[(size_t)t*DM + tid], o2);
        o_l[tid] = acc_o + o2;
    }
    __syncthreads();

    // ---- epilogue: out = o @ Wo + bo ----
    {
        float acc = bo[tid];
        for (int k = 0; k < DM; ++k)
            acc = fmaf(o_l[k], Wo[(size_t)k*DM + tid], acc);
        out[(size_t)bi*DM + tid] = acc;
    }
}

extern "C" void kernel_launch(void* const* d_in, const int* in_sizes, int n_in,
                              void* d_out, int out_size, void* d_ws, size_t ws_size,
                              hipStream_t stream) {
    const float* query = (const float*)d_in[0];
    const float* key_  = (const float*)d_in[1];
    const float* value = (const float*)d_in[2];
    const float* edges = (const float*)d_in[3];
    const int*   mask  = (const int*)d_in[4];
    const float* Wq = (const float*)d_in[5];
    const float* bq = (const float*)d_in[6];
    const float* Wk = (const float*)d_in[7];
    const float* bk = (const float*)d_in[8];
    const float* Wv = (const float*)d_in[9];
    const float* bv = (const float*)d_in[10];
    const float* Wo = (const float*)d_in[11];
    const float* bo = (const float*)d_in[12];
    const float* rkW1 = (const float*)d_in[13];
    const float* rkb1 = (const float*)d_in[14];
    const float* rkW2 = (const float*)d_in[15];
    const float* rkb2 = (const float*)d_in[16];
    const float* rvW1 = (const float*)d_in[17];
    const float* rvb1 = (const float*)d_in[18];
    const float* rvW2 = (const float*)d_in[19];
    const float* rvb2 = (const float*)d_in[20];
    // d_in[21] (u) is softmax-invariant -> unused
    const float* vvec = (const float*)d_in[22];

    const int rows = in_sizes[0] / DM;   // b*n = 1024
    float* Qw = (float*)d_ws;
    float* Kw = Qw + (size_t)rows*DM;
    float* Vw = Kw + (size_t)rows*DM;

    hipLaunchKernelGGL(proj_kernel, dim3(rows/4), dim3(256), 0, stream,
                       query, key_, value, Wq, bq, Wk, bk, Wv, bv, Qw, Kw, Vw);
    hipLaunchKernelGGL(attn_kernel, dim3(rows), dim3(256), 0, stream,
                       edges, mask, rkW1, rkb1, rkW2, rkb2, rvW1, rvb1, rvW2, rvb2,
                       vvec, Wo, bo, Qw, Kw, Vw, (float*)d_out);
}